// Round 4
// baseline (259.398 us; speedup 1.0000x reference)
//
#include <hip/hip_runtime.h>
#include <cstdint>

#define TOKENS 16384   // b*l = 4*4096
#define DIM 1024
#define NQ 1040        // 16 heads * 65 q-slots
#define NK 1024        // 16 * 64
#define NTOT 3088      // NQ + NK + NK (q | k | v)
#define NMAIN 3072     // 12 x 256 tiles in the big GEMM; last 16 cols via k_gemm
#define NPAD 3328      // Wall rows (zeros 3088..3327)
#define NKT 16         // K = 1024 = 16 K-tiles of 64

typedef __bf16 bf16_t;
typedef bf16_t bf16x8 __attribute__((ext_vector_type(8)));
typedef float f32x4 __attribute__((ext_vector_type(4)));

static __device__ __forceinline__ float bf2f(unsigned short u) {
    union { unsigned int i; float f; } v; v.i = ((unsigned int)u) << 16; return v.f;
}
static __device__ __forceinline__ unsigned short f2bf(float f) {
    unsigned int u = __float_as_uint(f);
    unsigned int r = u + 0x7FFFu + ((u >> 16) & 1u);   // RNE
    return (unsigned short)(r >> 16);
}

// async global->LDS, 16B/lane; LDS dest is wave-uniform base + lane*16B (linear).
static __device__ __forceinline__ void gload_lds16(const void* g, void* l) {
    __builtin_amdgcn_global_load_lds(
        (__attribute__((address_space(1))) void*)(uintptr_t)g,
        (__attribute__((address_space(3))) void*)(unsigned int)(uintptr_t)l,
        16, 0, 0);
}

// ---------------- merged cast kernel: x -> xb | build Wall | Wo -> Wob ----------------
#define XN4   (TOKENS * DIM / 4)            // 4,194,304
#define WALLN4 (NPAD * DIM / 4)             //   851,968
#define WON4  (DIM * DIM / 4)               //   262,144
#define CASTN4 (XN4 + WALLN4 + WON4)
__global__ __launch_bounds__(256) void k_cast_all(const float* __restrict__ x,
                                                  const float* __restrict__ Wq,
                                                  const float* __restrict__ Wk,
                                                  const float* __restrict__ Wv,
                                                  const float* __restrict__ Wo,
                                                  unsigned short* __restrict__ xb,
                                                  unsigned short* __restrict__ Wall,
                                                  unsigned short* __restrict__ Wob) {
    int i = blockIdx.x * 256 + threadIdx.x;
    if (i >= CASTN4) return;
    float4 v;
    unsigned short* dst;
    if (i < XN4) {
        v = ((const float4*)x)[i];
        dst = xb + (size_t)i * 4;
    } else if (i < XN4 + WALLN4) {
        int j = i - XN4;
        int c4 = j & 255;          // DIM/4 = 256
        int r  = j >> 8;
        if (r < NQ)              v = ((const float4*)Wq)[r * 256 + c4];
        else if (r < NQ + NK)    v = ((const float4*)Wk)[(r - NQ) * 256 + c4];
        else if (r < NTOT)       v = ((const float4*)Wv)[(r - (NQ + NK)) * 256 + c4];
        else                     v = make_float4(0.f, 0.f, 0.f, 0.f);
        dst = Wall + (size_t)j * 4;
    } else {
        int j = i - XN4 - WALLN4;
        v = ((const float4*)Wo)[j];
        dst = Wob + (size_t)j * 4;
    }
    ushort4 o;
    o.x = f2bf(v.x); o.y = f2bf(v.y); o.z = f2bf(v.z); o.w = f2bf(v.w);
    *(ushort4*)dst = o;
}

// ---------------- 128x128 m97-structure GEMM (round-2 verified) — remainder cols ----------------
template<int ADD_BIAS, int OUT_F32>
__global__ __launch_bounds__(256) void k_gemm(const unsigned short* __restrict__ A, int lda,
                                              const unsigned short* __restrict__ Bt, int ldb,
                                              void* __restrict__ Cout, int ldc, int nstore,
                                              const float* __restrict__ bias, int K) {
    __shared__ unsigned short Al[128 * 32];
    __shared__ unsigned short Bl[128 * 32];
    const int tid  = threadIdx.x;
    const int wid  = tid >> 6;
    const int lane = tid & 63;

    const int nbx = gridDim.x;
    const int nb  = nbx * gridDim.y;
    const int L   = blockIdx.y * nbx + blockIdx.x;
    const int q8  = nb >> 3, r8 = nb & 7;
    const int xcd = L & 7;
    const int idx = L >> 3;
    const int newid = (xcd < r8) ? xcd * (q8 + 1) + idx
                                 : r8 * (q8 + 1) + (xcd - r8) * q8 + idx;
    const int tm = (newid / nbx) * 128;
    const int tn = (newid % nbx) * 128;

    const int srow = lane >> 2;
    const int scol = (lane & 3) * 8;
    const unsigned short* Ag0 = A + (size_t)(tm + wid * 32 + srow) * lda + scol;
    const unsigned short* Ag1 = Ag0 + (size_t)16 * lda;
    const unsigned short* Bg0 = Bt + (size_t)(tn + wid * 32 + srow) * ldb + scol;
    const unsigned short* Bg1 = Bg0 + (size_t)16 * ldb;
    unsigned short* Al0 = &Al[(wid * 2 + 0) * 512];
    unsigned short* Al1 = &Al[(wid * 2 + 1) * 512];
    unsigned short* Bl0 = &Bl[(wid * 2 + 0) * 512];
    unsigned short* Bl1 = &Bl[(wid * 2 + 1) * 512];

    const int fr = lane & 15;
    const int fq = lane >> 4;
    const int wr = (wid >> 1) * 64;
    const int wc = (wid & 1) * 64;

    f32x4 acc[4][4] = {};

    for (int k0 = 0; k0 < K; k0 += 32) {
        gload_lds16(Ag0 + k0, Al0);
        gload_lds16(Ag1 + k0, Al1);
        gload_lds16(Bg0 + k0, Bl0);
        gload_lds16(Bg1 + k0, Bl1);
        __syncthreads();
        bf16x8 af[4], bfv[4];
#pragma unroll
        for (int m = 0; m < 4; ++m)
            af[m] = *(const bf16x8*)&Al[(wr + m * 16 + fr) * 32 + fq * 8];
#pragma unroll
        for (int n = 0; n < 4; ++n)
            bfv[n] = *(const bf16x8*)&Bl[(wc + n * 16 + fr) * 32 + fq * 8];
#pragma unroll
        for (int m = 0; m < 4; ++m)
#pragma unroll
            for (int n = 0; n < 4; ++n)
                acc[m][n] = __builtin_amdgcn_mfma_f32_16x16x32_bf16(af[m], bfv[n], acc[m][n], 0, 0, 0);
        __syncthreads();
    }

#pragma unroll
    for (int m = 0; m < 4; ++m) {
        const int row0 = tm + wr + m * 16 + fq * 4;
#pragma unroll
        for (int n = 0; n < 4; ++n) {
            const int col = tn + wc + n * 16 + fr;
            if (col < nstore) {
                f32x4 v = acc[m][n];
                float b = ADD_BIAS ? bias[col] : 0.0f;
#pragma unroll
                for (int j = 0; j < 4; ++j) {
                    const size_t idx2 = (size_t)(row0 + j) * ldc + col;
                    if (OUT_F32) ((float*)Cout)[idx2] = v[j] + b;
                    else         ((unsigned short*)Cout)[idx2] = f2bf(v[j] + b);
                }
            }
        }
    }
}

// ============ 256x256x(BK=64) 8-phase bf16 GEMM: C[M,N] = A[M,K] * Bt[N,K]^T ============
// (round-3 verified schedule, untouched; only grids change this round)
template<int ADD_BIAS, int OUT_F32>
__global__ __launch_bounds__(512, 2) void k_gemm256(const unsigned short* __restrict__ A, int lda,
                                                    const unsigned short* __restrict__ Bt, int ldb,
                                                    void* __restrict__ Cout, int ldc, int nstore,
                                                    const float* __restrict__ bias) {
    __shared__ char smem[131072];
    const int tid  = threadIdx.x;
    const int wid  = tid >> 6;          // 0..7
    const int lane = tid & 63;
    const int wm = wid >> 2;            // 0..1  (M half)
    const int wn = wid & 3;             // 0..3  (N quarter)
    const int fr = lane & 15;
    const int fq = lane >> 4;
    const int fr7 = fr & 7;
    const int srow8  = lane >> 3;                        // staging row-in-chunk
    const int cperm8 = ((lane & 7) ^ srow8) * 8;         // staging col perm (elements)

    // XCD-chunked bijective swizzle (nb divisible by 8 for both GEMMs)
    const int nbx = gridDim.x;
    const int nb  = nbx * gridDim.y;
    const int L   = blockIdx.y * nbx + blockIdx.x;
    const int q8  = nb >> 3;
    const int newid = (L & 7) * q8 + (L >> 3);
    const int tm = (newid / nbx) * 256;
    const int tn = (newid % nbx) * 256;

#define STAGE(ptr, ld, tile0, kt2, h, matbase)                                              \
    {                                                                                        \
        _Pragma("unroll")                                                                    \
        for (int j = 0; j < 2; ++j) {                                                        \
            const int c = wid * 2 + j;                                                       \
            const unsigned short* src = (ptr) +                                              \
                (size_t)((tile0) + (h) * 128 + c * 8 + srow8) * (ld) + (kt2) * 64 + cperm8;  \
            char* dst = (char*)smem + ((((kt2) & 1) << 16) | (matbase) | ((h) << 14) | (c << 10)); \
            gload_lds16(src, dst);                                                           \
        }                                                                                    \
    }
#define STAGE_A(kt2, h) STAGE(A, lda, tm, kt2, h, 0)
#define STAGE_B(kt2, h) STAGE(Bt, ldb, tn, kt2, h, 32768)

    const int sx0 = ((0 + fq) ^ fr7) << 4;              // ks=0 16B slot (swizzled)
    const int sx1 = ((4 + fq) ^ fr7) << 4;              // ks=1
    const int aoff = (wm << 14) + (fr << 7);
    const int boff = 32768 + ((wn >> 1) << 14) + ((((wn & 1) * 64) + fr) << 7);

    bf16x8 a[4][2], b0[2][2], b1[2][2];
    f32x4 acc[8][4] = {};

#define READ_A(kb, mh)                                                                       \
    { _Pragma("unroll")                                                                      \
      for (int i = 0; i < 4; ++i) {                                                          \
        a[i][0] = *(const bf16x8*)(smem + (kb) + aoff + (((mh) * 64 + i * 16) << 7) + sx0);  \
        a[i][1] = *(const bf16x8*)(smem + (kb) + aoff + (((mh) * 64 + i * 16) << 7) + sx1);  \
      } }
#define READ_B(kb, nh, breg)                                                                 \
    { _Pragma("unroll")                                                                      \
      for (int n2 = 0; n2 < 2; ++n2) {                                                       \
        breg[n2][0] = *(const bf16x8*)(smem + (kb) + boff + ((((nh) * 2 + n2) * 16) << 7) + sx0); \
        breg[n2][1] = *(const bf16x8*)(smem + (kb) + boff + ((((nh) * 2 + n2) * 16) << 7) + sx1); \
      } }
#define MFMA_Q(mh, nh, breg)                                                                 \
    { _Pragma("unroll")                                                                      \
      for (int i = 0; i < 4; ++i)                                                            \
        _Pragma("unroll")                                                                    \
        for (int n2 = 0; n2 < 2; ++n2) {                                                     \
          acc[(mh) * 4 + i][(nh) * 2 + n2] = __builtin_amdgcn_mfma_f32_16x16x32_bf16(        \
              a[i][0], breg[n2][0], acc[(mh) * 4 + i][(nh) * 2 + n2], 0, 0, 0);              \
          acc[(mh) * 4 + i][(nh) * 2 + n2] = __builtin_amdgcn_mfma_f32_16x16x32_bf16(        \
              a[i][1], breg[n2][1], acc[(mh) * 4 + i][(nh) * 2 + n2], 0, 0, 0);              \
        } }
#define SYNC_PRE()                                             \
    __builtin_amdgcn_s_barrier();                              \
    asm volatile("s_waitcnt lgkmcnt(0)" ::: "memory");         \
    __builtin_amdgcn_sched_barrier(0);                         \
    __builtin_amdgcn_s_setprio(1);
#define SYNC_POST()                                            \
    __builtin_amdgcn_s_setprio(0);                             \
    __builtin_amdgcn_s_barrier();

    // ---- prologue: kt0 fully + kt1's B halves; drain the kt0 stages ----
    STAGE_A(0, 0); STAGE_A(0, 1); STAGE_B(0, 0); STAGE_B(0, 1);
    STAGE_B(1, 0); STAGE_B(1, 1);
    asm volatile("s_waitcnt vmcnt(4)" ::: "memory");
    __builtin_amdgcn_s_barrier();

    for (int kt = 0; kt < NKT; ++kt) {
        const int kb = (kt & 1) << 16;
        // ---- P0 ----
        READ_A(kb, 0);
        READ_B(kb, 0, b0);
        if (kt < NKT - 1) STAGE_A(kt + 1, 0);
        asm volatile("s_waitcnt lgkmcnt(8)" ::: "memory");
        SYNC_PRE(); MFMA_Q(0, 0, b0); SYNC_POST();
        // ---- P1 ----
        READ_B(kb, 1, b1);
        if (kt < NKT - 1) STAGE_A(kt + 1, 1);
        SYNC_PRE(); MFMA_Q(0, 1, b1); SYNC_POST();
        // ---- P2 ----
        READ_A(kb, 1);
        if (kt < NKT - 2) STAGE_B(kt + 2, 0);
        SYNC_PRE(); MFMA_Q(1, 1, b1); SYNC_POST();
        // ---- P3 (no ds_read; uses regs a[mh1], b0) ----
        if (kt < NKT - 2) STAGE_B(kt + 2, 1);
        __builtin_amdgcn_s_barrier();
        __builtin_amdgcn_s_setprio(1); MFMA_Q(1, 0, b0); __builtin_amdgcn_s_setprio(0);
        if (kt < NKT - 2) { asm volatile("s_waitcnt vmcnt(4)" ::: "memory"); }
        else              { asm volatile("s_waitcnt vmcnt(0)" ::: "memory"); }
        __builtin_amdgcn_s_barrier();
    }

    // ---- epilogue: C write ----
#pragma unroll
    for (int mq = 0; mq < 8; ++mq) {
        const int row0 = tm + wm * 128 + mq * 16 + fq * 4;
#pragma unroll
        for (int nf = 0; nf < 4; ++nf) {
            const int col = tn + wn * 64 + nf * 16 + fr;
            if (col < nstore) {
                f32x4 v = acc[mq][nf];
                const float bb = ADD_BIAS ? bias[col] : 0.0f;
#pragma unroll
                for (int j = 0; j < 4; ++j) {
                    const size_t idx = (size_t)(row0 + j) * ldc + col;
                    if (OUT_F32) ((float*)Cout)[idx] = v[j] + bb;
                    else         ((unsigned short*)Cout)[idx] = f2bf(v[j] + bb);
                }
            }
        }
    }
#undef STAGE
#undef STAGE_A
#undef STAGE_B
#undef READ_A
#undef READ_B
#undef MFMA_Q
#undef SYNC_PRE
#undef SYNC_POST
}

// ---------------- gating: per-token per-head softmaxes, write g over v-section ----------------
__global__ __launch_bounds__(256) void k_gate(unsigned short* __restrict__ C1,
                                              const float* __restrict__ mask) {
    const int t    = blockIdx.x;
    const int wid  = threadIdx.x >> 6;
    const int lane = threadIdx.x & 63;
    unsigned short* row = C1 + (size_t)t * NTOT;
    const float mk = mask[t];
#pragma unroll
    for (int hh = 0; hh < 4; ++hh) {
        const int h = wid * 4 + hh;
        float ql  = bf2f(row[h * 65 + lane]);
        float q64 = bf2f(row[h * 65 + 64]);
        float m = ql;
        for (int o = 32; o; o >>= 1) m = fmaxf(m, __shfl_xor(m, o));
        m = fmaxf(m, q64);
        float e = __expf(ql - m);
        float s = e;
        for (int o = 32; o; o >>= 1) s += __shfl_xor(s, o);
        float e64 = __expf(q64 - m);
        s += e64;
        const float w = 2.0f * (1.0f - e64 / s);   // qk_weight
        float kl = bf2f(row[NQ + h * 64 + lane]);
        float km = kl;
        for (int o = 32; o; o >>= 1) km = fmaxf(km, __shfl_xor(km, o));
        float ke = __expf(kl - km);
        float ks = ke;
        for (int o = 32; o; o >>= 1) ks += __shfl_xor(ks, o);
        const float ksm = ke / ks;
        const int vi = NQ + NK + h * 64 + lane;
        const float v = bf2f(row[vi]);
        row[vi] = f2bf(w * ksm * v * mk);
    }
}

extern "C" void kernel_launch(void* const* d_in, const int* in_sizes, int n_in,
                              void* d_out, int out_size, void* d_ws, size_t ws_size,
                              hipStream_t stream) {
    (void)in_sizes; (void)n_in; (void)out_size; (void)ws_size;
    const float* x  = (const float*)d_in[0];
    const float* am = (const float*)d_in[1];
    const float* Wq = (const float*)d_in[2];
    const float* Wk = (const float*)d_in[3];
    const float* Wv = (const float*)d_in[4];
    const float* Wo = (const float*)d_in[5];
    const float* bo = (const float*)d_in[6];
    // time_angle / head_time_delta collapse to the constant 2 (see round-0 analysis)

    char* ws = (char*)d_ws;
    unsigned short* xb   = (unsigned short*)(ws);                  // 16384x1024 bf16   33,554,432 B
    unsigned short* Wall = (unsigned short*)(ws + 33554432);       // 3328x1024 bf16     6,815,744 B
    unsigned short* Wob  = (unsigned short*)(ws + 40370176);       // 1024x1024 bf16     2,097,152 B
    unsigned short* C1   = (unsigned short*)(ws + 42467328);       // 16384x3088 bf16  101,187,584 B

    // fused casts (x->bf16, Wall build, Wo->bf16)
    k_cast_all<<<dim3((CASTN4 + 255) / 256), 256, 0, stream>>>(x, Wq, Wk, Wv, Wo, xb, Wall, Wob);

    // GEMM1 main: C1 cols [0,3072) = xb @ Wall[0:3072]^T — 768 blocks = exactly 3 rounds
    k_gemm256<0, 0><<<dim3(NMAIN / 256, TOKENS / 256), 512, 0, stream>>>(
        xb, DIM, Wall, DIM, C1, NTOT, NMAIN, nullptr);

    // GEMM1 remainder: C1 cols [3072,3088) (v head15 slots 48..63) via 128-tile kernel
    k_gemm<0, 0><<<dim3(1, TOKENS / 128), 256, 0, stream>>>(
        xb, DIM, Wall + (size_t)3072 * DIM, DIM, C1 + 3072, NTOT, 16, nullptr, DIM);

    // gating softmaxes, writes g over the v-section of C1
    k_gate<<<dim3(TOKENS), 256, 0, stream>>>(C1, am);

    // GEMM2: out[16384,1024] = g @ Wo^T + bo  (A = C1 v-section, lda=3088, f32 out) — 256 blocks
    k_gemm256<1, 1><<<dim3(DIM / 256, TOKENS / 256), 512, 0, stream>>>(
        C1 + (NQ + NK), NTOT, Wob, DIM, d_out, DIM, DIM, bo);
}

// Round 5
// 245.406 us; speedup vs baseline: 1.0570x; 1.0570x over previous
//
#include <hip/hip_runtime.h>
#include <cstdint>

#define TOKENS 16384   // b*l = 4*4096
#define DIM 1024
#define NW 3072        // GEMM1 N: q-slots0-63 (1024) | k (1024) | v (1024) = 12 x 256
#define NKT 16         // K = 1024 = 16 K-tiles of 64

typedef __bf16 bf16_t;
typedef bf16_t bf16x8 __attribute__((ext_vector_type(8)));
typedef unsigned short u16x8 __attribute__((ext_vector_type(8)));
typedef float f32x4 __attribute__((ext_vector_type(4)));

static __device__ __forceinline__ float bf2f(unsigned short u) {
    union { unsigned int i; float f; } v; v.i = ((unsigned int)u) << 16; return v.f;
}
static __device__ __forceinline__ unsigned short f2bf(float f) {
    unsigned int u = __float_as_uint(f);
    unsigned int r = u + 0x7FFFu + ((u >> 16) & 1u);   // RNE
    return (unsigned short)(r >> 16);
}

// async global->LDS, 16B/lane; LDS dest is wave-uniform base + lane*16B (linear).
static __device__ __forceinline__ void gload_lds16(const void* g, void* l) {
    __builtin_amdgcn_global_load_lds(
        (__attribute__((address_space(1))) void*)(uintptr_t)g,
        (__attribute__((address_space(3))) void*)(unsigned int)(uintptr_t)l,
        16, 0, 0);
}

// ---------------- merged cast kernel: x->xb | build Wall | Wq64 | Wo->Wob ----------------
// Wall[3072][1024]: rows [0,1024)=Wq(head h slot s -> h*65+s, s<64), [1024,2048)=Wk, [2048,3072)=Wv
// Wq64[16][1024]: Wq rows h*65+64 (per-head slot-64 projection, used by k_gate)
#define XN4    (TOKENS * DIM / 4)           // 4,194,304
#define WALLN4 (NW * DIM / 4)               //   786,432
#define WQ64N4 (16 * DIM / 4)               //     4,096
#define WON4   (DIM * DIM / 4)              //   262,144
#define CASTN4 (XN4 + WALLN4 + WQ64N4 + WON4)
__global__ __launch_bounds__(256) void k_cast_all(const float* __restrict__ x,
                                                  const float* __restrict__ Wq,
                                                  const float* __restrict__ Wk,
                                                  const float* __restrict__ Wv,
                                                  const float* __restrict__ Wo,
                                                  unsigned short* __restrict__ xb,
                                                  unsigned short* __restrict__ Wall,
                                                  unsigned short* __restrict__ Wq64b,
                                                  unsigned short* __restrict__ Wob) {
    int i = blockIdx.x * 256 + threadIdx.x;
    if (i >= CASTN4) return;
    float4 v;
    unsigned short* dst;
    if (i < XN4) {
        v = ((const float4*)x)[i];
        dst = xb + (size_t)i * 4;
    } else if (i < XN4 + WALLN4) {
        int j = i - XN4;
        int c4 = j & 255;          // DIM/4 = 256
        int r  = j >> 8;
        if (r < 1024)            v = ((const float4*)Wq)[((r >> 6) * 65 + (r & 63)) * 256 + c4];
        else if (r < 2048)       v = ((const float4*)Wk)[(r - 1024) * 256 + c4];
        else                     v = ((const float4*)Wv)[(r - 2048) * 256 + c4];
        dst = Wall + (size_t)j * 4;
    } else if (i < XN4 + WALLN4 + WQ64N4) {
        int j = i - XN4 - WALLN4;
        int c4 = j & 255;
        int h  = j >> 8;
        v = ((const float4*)Wq)[(h * 65 + 64) * 256 + c4];
        dst = Wq64b + (size_t)j * 4;
    } else {
        int j = i - XN4 - WALLN4 - WQ64N4;
        v = ((const float4*)Wo)[j];
        dst = Wob + (size_t)j * 4;
    }
    ushort4 o;
    o.x = f2bf(v.x); o.y = f2bf(v.y); o.z = f2bf(v.z); o.w = f2bf(v.w);
    *(ushort4*)dst = o;
}

// ============ 256x256x(BK=64) 8-phase bf16 GEMM: C[M,N] = A[M,K] * Bt[N,K]^T ============
// (round-3/4 verified schedule, untouched)
template<int ADD_BIAS, int OUT_F32>
__global__ __launch_bounds__(512, 2) void k_gemm256(const unsigned short* __restrict__ A, int lda,
                                                    const unsigned short* __restrict__ Bt, int ldb,
                                                    void* __restrict__ Cout, int ldc, int nstore,
                                                    const float* __restrict__ bias) {
    __shared__ char smem[131072];
    const int tid  = threadIdx.x;
    const int wid  = tid >> 6;          // 0..7
    const int lane = tid & 63;
    const int wm = wid >> 2;            // 0..1  (M half)
    const int wn = wid & 3;             // 0..3  (N quarter)
    const int fr = lane & 15;
    const int fq = lane >> 4;
    const int fr7 = fr & 7;
    const int srow8  = lane >> 3;                        // staging row-in-chunk
    const int cperm8 = ((lane & 7) ^ srow8) * 8;         // staging col perm (elements)

    // XCD-chunked bijective swizzle (nb divisible by 8 for both GEMMs)
    const int nbx = gridDim.x;
    const int nb  = nbx * gridDim.y;
    const int L   = blockIdx.y * nbx + blockIdx.x;
    const int q8  = nb >> 3;
    const int newid = (L & 7) * q8 + (L >> 3);
    const int tm = (newid / nbx) * 256;
    const int tn = (newid % nbx) * 256;

#define STAGE(ptr, ld, tile0, kt2, h, matbase)                                              \
    {                                                                                        \
        _Pragma("unroll")                                                                    \
        for (int j = 0; j < 2; ++j) {                                                        \
            const int c = wid * 2 + j;                                                       \
            const unsigned short* src = (ptr) +                                              \
                (size_t)((tile0) + (h) * 128 + c * 8 + srow8) * (ld) + (kt2) * 64 + cperm8;  \
            char* dst = (char*)smem + ((((kt2) & 1) << 16) | (matbase) | ((h) << 14) | (c << 10)); \
            gload_lds16(src, dst);                                                           \
        }                                                                                    \
    }
#define STAGE_A(kt2, h) STAGE(A, lda, tm, kt2, h, 0)
#define STAGE_B(kt2, h) STAGE(Bt, ldb, tn, kt2, h, 32768)

    const int sx0 = ((0 + fq) ^ fr7) << 4;              // ks=0 16B slot (swizzled)
    const int sx1 = ((4 + fq) ^ fr7) << 4;              // ks=1
    const int aoff = (wm << 14) + (fr << 7);
    const int boff = 32768 + ((wn >> 1) << 14) + ((((wn & 1) * 64) + fr) << 7);

    bf16x8 a[4][2], b0[2][2], b1[2][2];
    f32x4 acc[8][4] = {};

#define READ_A(kb, mh)                                                                       \
    { _Pragma("unroll")                                                                      \
      for (int i = 0; i < 4; ++i) {                                                          \
        a[i][0] = *(const bf16x8*)(smem + (kb) + aoff + (((mh) * 64 + i * 16) << 7) + sx0);  \
        a[i][1] = *(const bf16x8*)(smem + (kb) + aoff + (((mh) * 64 + i * 16) << 7) + sx1);  \
      } }
#define READ_B(kb, nh, breg)                                                                 \
    { _Pragma("unroll")                                                                      \
      for (int n2 = 0; n2 < 2; ++n2) {                                                       \
        breg[n2][0] = *(const bf16x8*)(smem + (kb) + boff + ((((nh) * 2 + n2) * 16) << 7) + sx0); \
        breg[n2][1] = *(const bf16x8*)(smem + (kb) + boff + ((((nh) * 2 + n2) * 16) << 7) + sx1); \
      } }
#define MFMA_Q(mh, nh, breg)                                                                 \
    { _Pragma("unroll")                                                                      \
      for (int i = 0; i < 4; ++i)                                                            \
        _Pragma("unroll")                                                                    \
        for (int n2 = 0; n2 < 2; ++n2) {                                                     \
          acc[(mh) * 4 + i][(nh) * 2 + n2] = __builtin_amdgcn_mfma_f32_16x16x32_bf16(        \
              a[i][0], breg[n2][0], acc[(mh) * 4 + i][(nh) * 2 + n2], 0, 0, 0);              \
          acc[(mh) * 4 + i][(nh) * 2 + n2] = __builtin_amdgcn_mfma_f32_16x16x32_bf16(        \
              a[i][1], breg[n2][1], acc[(mh) * 4 + i][(nh) * 2 + n2], 0, 0, 0);              \
        } }
#define SYNC_PRE()                                             \
    __builtin_amdgcn_s_barrier();                              \
    asm volatile("s_waitcnt lgkmcnt(0)" ::: "memory");         \
    __builtin_amdgcn_sched_barrier(0);                         \
    __builtin_amdgcn_s_setprio(1);
#define SYNC_POST()                                            \
    __builtin_amdgcn_s_setprio(0);                             \
    __builtin_amdgcn_s_barrier();

    // ---- prologue: kt0 fully + kt1's B halves; drain the kt0 stages ----
    STAGE_A(0, 0); STAGE_A(0, 1); STAGE_B(0, 0); STAGE_B(0, 1);
    STAGE_B(1, 0); STAGE_B(1, 1);
    asm volatile("s_waitcnt vmcnt(4)" ::: "memory");
    __builtin_amdgcn_s_barrier();

    for (int kt = 0; kt < NKT; ++kt) {
        const int kb = (kt & 1) << 16;
        // ---- P0 ----
        READ_A(kb, 0);
        READ_B(kb, 0, b0);
        if (kt < NKT - 1) STAGE_A(kt + 1, 0);
        asm volatile("s_waitcnt lgkmcnt(8)" ::: "memory");
        SYNC_PRE(); MFMA_Q(0, 0, b0); SYNC_POST();
        // ---- P1 ----
        READ_B(kb, 1, b1);
        if (kt < NKT - 1) STAGE_A(kt + 1, 1);
        SYNC_PRE(); MFMA_Q(0, 1, b1); SYNC_POST();
        // ---- P2 ----
        READ_A(kb, 1);
        if (kt < NKT - 2) STAGE_B(kt + 2, 0);
        SYNC_PRE(); MFMA_Q(1, 1, b1); SYNC_POST();
        // ---- P3 (no ds_read; uses regs a[mh1], b0) ----
        if (kt < NKT - 2) STAGE_B(kt + 2, 1);
        __builtin_amdgcn_s_barrier();
        __builtin_amdgcn_s_setprio(1); MFMA_Q(1, 0, b0); __builtin_amdgcn_s_setprio(0);
        if (kt < NKT - 2) { asm volatile("s_waitcnt vmcnt(4)" ::: "memory"); }
        else              { asm volatile("s_waitcnt vmcnt(0)" ::: "memory"); }
        __builtin_amdgcn_s_barrier();
    }

    // ---- epilogue: C write ----
#pragma unroll
    for (int mq = 0; mq < 8; ++mq) {
        const int row0 = tm + wm * 128 + mq * 16 + fq * 4;
#pragma unroll
        for (int nf = 0; nf < 4; ++nf) {
            const int col = tn + wn * 64 + nf * 16 + fr;
            if (col < nstore) {
                f32x4 v = acc[mq][nf];
                const float bb = ADD_BIAS ? bias[col] : 0.0f;
#pragma unroll
                for (int j = 0; j < 4; ++j) {
                    const size_t idx = (size_t)(row0 + j) * ldc + col;
                    if (OUT_F32) ((float*)Cout)[idx] = v[j] + bb;
                    else         ((unsigned short*)Cout)[idx] = f2bf(v[j] + bb);
                }
            }
        }
    }
#undef STAGE
#undef STAGE_A
#undef STAGE_B
#undef READ_A
#undef READ_B
#undef MFMA_Q
#undef SYNC_PRE
#undef SYNC_POST
}

// ---------------- gating: per-token per-head softmaxes + in-kernel slot-64 q-logit ----------------
// C1 row layout (stride 3072): [0,1024) q-logits slots0-63 | [1024,2048) k-logits | [2048,3072) v
__global__ __launch_bounds__(256) void k_gate(const unsigned short* __restrict__ xb,
                                              const unsigned short* __restrict__ Wq64,
                                              unsigned short* __restrict__ C1,
                                              const float* __restrict__ mask) {
    const int t    = blockIdx.x;
    const int wid  = threadIdx.x >> 6;
    const int lane = threadIdx.x & 63;
    unsigned short* row = C1 + (size_t)t * NW;
    const float mk = mask[t];
    // per-lane 16-element chunk of this token's x row (bf16)
    const unsigned short* xrow = xb + (size_t)t * DIM + lane * 16;
    const u16x8 xv0 = *(const u16x8*)(xrow);
    const u16x8 xv1 = *(const u16x8*)(xrow + 8);
#pragma unroll
    for (int hh = 0; hh < 4; ++hh) {
        const int h = wid * 4 + hh;
        // q64 = dot(x_row, Wq64[h]) — the slot-64 logit the GEMM no longer computes
        const unsigned short* wrow = Wq64 + (size_t)h * DIM + lane * 16;
        const u16x8 wv0 = *(const u16x8*)(wrow);
        const u16x8 wv1 = *(const u16x8*)(wrow + 8);
        float d = 0.f;
#pragma unroll
        for (int j = 0; j < 8; ++j)
            d += bf2f(xv0[j]) * bf2f(wv0[j]) + bf2f(xv1[j]) * bf2f(wv1[j]);
        for (int o = 32; o; o >>= 1) d += __shfl_xor(d, o);
        const float q64 = d;
        // q softmax over 65 slots -> last-slot probability
        float ql = bf2f(row[h * 64 + lane]);
        float m = ql;
        for (int o = 32; o; o >>= 1) m = fmaxf(m, __shfl_xor(m, o));
        m = fmaxf(m, q64);
        float e = __expf(ql - m);
        float s = e;
        for (int o = 32; o; o >>= 1) s += __shfl_xor(s, o);
        float e64 = __expf(q64 - m);
        s += e64;
        const float w = 2.0f * (1.0f - e64 / s);   // qk_weight
        // k softmax over 64 slots
        float kl = bf2f(row[1024 + h * 64 + lane]);
        float km = kl;
        for (int o = 32; o; o >>= 1) km = fmaxf(km, __shfl_xor(km, o));
        float ke = __expf(kl - km);
        float ks = ke;
        for (int o = 32; o; o >>= 1) ks += __shfl_xor(ks, o);
        const float ksm = ke / ks;
        // gate v in place
        const int vi = 2048 + h * 64 + lane;
        const float v = bf2f(row[vi]);
        row[vi] = f2bf(w * ksm * v * mk);
    }
}

extern "C" void kernel_launch(void* const* d_in, const int* in_sizes, int n_in,
                              void* d_out, int out_size, void* d_ws, size_t ws_size,
                              hipStream_t stream) {
    (void)in_sizes; (void)n_in; (void)out_size; (void)ws_size;
    const float* x  = (const float*)d_in[0];
    const float* am = (const float*)d_in[1];
    const float* Wq = (const float*)d_in[2];
    const float* Wk = (const float*)d_in[3];
    const float* Wv = (const float*)d_in[4];
    const float* Wo = (const float*)d_in[5];
    const float* bo = (const float*)d_in[6];
    // time_angle / head_time_delta collapse to the constant 2 (see round-0 analysis)

    char* ws = (char*)d_ws;
    unsigned short* xb    = (unsigned short*)(ws);                 // 16384x1024 bf16   33,554,432 B
    unsigned short* Wall  = (unsigned short*)(ws + 33554432);      // 3072x1024 bf16     6,291,456 B
    unsigned short* Wq64b = (unsigned short*)(ws + 39845888);      // 16x1024 bf16          32,768 B
    unsigned short* Wob   = (unsigned short*)(ws + 39878656);      // 1024x1024 bf16     2,097,152 B
    unsigned short* C1    = (unsigned short*)(ws + 41975808);      // 16384x3072 bf16  100,663,296 B

    // fused casts (x->bf16, Wall build, Wq64, Wo->bf16)
    k_cast_all<<<dim3((CASTN4 + 255) / 256), 256, 0, stream>>>(
        x, Wq, Wk, Wv, Wo, xb, Wall, Wq64b, Wob);

    // GEMM1: C1[16384,3072] = xb @ Wall^T — 768 blocks = exactly 3 full rounds
    k_gemm256<0, 0><<<dim3(NW / 256, TOKENS / 256), 512, 0, stream>>>(
        xb, DIM, Wall, DIM, C1, NW, NW, nullptr);

    // gating softmaxes (incl. in-kernel q64 dot), writes g over the v-section of C1
    k_gate<<<dim3(TOKENS), 256, 0, stream>>>(xb, Wq64b, C1, am);

    // GEMM2: out[16384,1024] = g @ Wo^T + bo  (A = C1 v-section, lda=3072, f32 out) — 256 blocks
    k_gemm256<1, 1><<<dim3(DIM / 256, TOKENS / 256), 512, 0, stream>>>(
        C1 + 2048, NW, Wob, DIM, d_out, DIM, DIM, bo);
}

// Round 6
// 222.979 us; speedup vs baseline: 1.1633x; 1.1006x over previous
//
#include <hip/hip_runtime.h>
#include <cstdint>

#define TOKENS 16384   // b*l = 4*4096
#define DIM 1024
#define NW 3072        // GEMM1 N: q-slots0-63 (1024) | k (1024) | v (1024) = 12 x 256
#define LDC1 2048      // C1 row stride: [ksm 1024 | v 1024]
#define NKT 16         // K = 1024 = 16 K-tiles of 64

typedef __bf16 bf16_t;
typedef bf16_t bf16x8 __attribute__((ext_vector_type(8)));
typedef unsigned short u16x8 __attribute__((ext_vector_type(8)));
typedef float f32x4 __attribute__((ext_vector_type(4)));

static __device__ __forceinline__ float bf2f(unsigned short u) {
    union { unsigned int i; float f; } v; v.i = ((unsigned int)u) << 16; return v.f;
}
static __device__ __forceinline__ unsigned short f2bf(float f) {
    unsigned int u = __float_as_uint(f);
    unsigned int r = u + 0x7FFFu + ((u >> 16) & 1u);   // RNE
    return (unsigned short)(r >> 16);
}

// async global->LDS, 16B/lane; LDS dest is wave-uniform base + lane*16B (linear).
static __device__ __forceinline__ void gload_lds16(const void* g, void* l) {
    __builtin_amdgcn_global_load_lds(
        (__attribute__((address_space(1))) void*)(uintptr_t)g,
        (__attribute__((address_space(3))) void*)(unsigned int)(uintptr_t)l,
        16, 0, 0);
}

// ---------------- merged cast kernel: x->xb | build Wall | Wq64 | Wo->Wob ----------------
// Wall[3072][1024]: rows [0,1024)=Wq(head h slot s -> h*65+s, s<64), [1024,2048)=Wk, [2048,3072)=Wv
// Wq64[16][1024]: Wq rows h*65+64 (per-head slot-64 projection)
#define XN4    (TOKENS * DIM / 4)           // 4,194,304
#define WALLN4 (NW * DIM / 4)               //   786,432
#define WQ64N4 (16 * DIM / 4)               //     4,096
#define WON4   (DIM * DIM / 4)              //   262,144
#define CASTN4 (XN4 + WALLN4 + WQ64N4 + WON4)
__global__ __launch_bounds__(256) void k_cast_all(const float* __restrict__ x,
                                                  const float* __restrict__ Wq,
                                                  const float* __restrict__ Wk,
                                                  const float* __restrict__ Wv,
                                                  const float* __restrict__ Wo,
                                                  unsigned short* __restrict__ xb,
                                                  unsigned short* __restrict__ Wall,
                                                  unsigned short* __restrict__ Wq64b,
                                                  unsigned short* __restrict__ Wob) {
    int i = blockIdx.x * 256 + threadIdx.x;
    if (i >= CASTN4) return;
    float4 v;
    unsigned short* dst;
    if (i < XN4) {
        v = ((const float4*)x)[i];
        dst = xb + (size_t)i * 4;
    } else if (i < XN4 + WALLN4) {
        int j = i - XN4;
        int c4 = j & 255;          // DIM/4 = 256
        int r  = j >> 8;
        if (r < 1024)            v = ((const float4*)Wq)[((r >> 6) * 65 + (r & 63)) * 256 + c4];
        else if (r < 2048)       v = ((const float4*)Wk)[(r - 1024) * 256 + c4];
        else                     v = ((const float4*)Wv)[(r - 2048) * 256 + c4];
        dst = Wall + (size_t)j * 4;
    } else if (i < XN4 + WALLN4 + WQ64N4) {
        int j = i - XN4 - WALLN4;
        int c4 = j & 255;
        int h  = j >> 8;
        v = ((const float4*)Wq)[(h * 65 + 64) * 256 + c4];
        dst = Wq64b + (size_t)j * 4;
    } else {
        int j = i - XN4 - WALLN4 - WQ64N4;
        v = ((const float4*)Wo)[j];
        dst = Wob + (size_t)j * 4;
    }
    ushort4 o;
    o.x = f2bf(v.x); o.y = f2bf(v.y); o.z = f2bf(v.z); o.w = f2bf(v.w);
    *(ushort4*)dst = o;
}

// ---------------- q64: per-token per-head slot-64 logit = dot(x_row, Wq64[h]) ----------------
// one wave per token (4 tokens per 256-thr block); 16 elems/lane held in regs
__global__ __launch_bounds__(256) void k_q64(const unsigned short* __restrict__ xb,
                                             const unsigned short* __restrict__ Wq64,
                                             float* __restrict__ q64) {
    const int t    = blockIdx.x * 4 + (threadIdx.x >> 6);
    const int lane = threadIdx.x & 63;
    const unsigned short* xrow = xb + (size_t)t * DIM + lane * 16;
    const u16x8 xv0 = *(const u16x8*)(xrow);
    const u16x8 xv1 = *(const u16x8*)(xrow + 8);
    float xf[16];
#pragma unroll
    for (int j = 0; j < 8; ++j) { xf[j] = bf2f(xv0[j]); xf[8 + j] = bf2f(xv1[j]); }
#pragma unroll
    for (int h = 0; h < 16; ++h) {
        const unsigned short* wrow = Wq64 + (size_t)h * DIM + lane * 16;
        const u16x8 wv0 = *(const u16x8*)(wrow);
        const u16x8 wv1 = *(const u16x8*)(wrow + 8);
        float d = 0.f;
#pragma unroll
        for (int j = 0; j < 8; ++j)
            d += xf[j] * bf2f(wv0[j]) + xf[8 + j] * bf2f(wv1[j]);
        for (int o = 32; o; o >>= 1) d += __shfl_xor(d, o);
        if (lane == 0) q64[(size_t)t * 16 + h] = d;
    }
}

// ============ 256x256x(BK=64) 8-phase bf16 GEMM (round-3/4/5 verified K-loop) ============
// FUSED=1 (GEMM1): epilogue branches on tile kind (tn>>10):
//   q-tiles  -> per-(row,head) softmax stats over the 64 in-tile logits + q64 -> wfac[t,h]
//   k-tiles  -> in-register softmax, store ksm bf16 at C1[t][tn-1024+...]
//   v-tiles  -> plain bf16 store at C1[t][tn-1024+...]
// FUSED=0 (GEMM2): f32 store + bias.
template<int FUSED>
__global__ __launch_bounds__(512, 2) void k_gemm256(const unsigned short* __restrict__ A, int lda,
                                                    const unsigned short* __restrict__ Bt, int ldb,
                                                    void* __restrict__ Cout, int ldc,
                                                    const float* __restrict__ bias,
                                                    const float* __restrict__ q64p,
                                                    float* __restrict__ wfac) {
    __shared__ char smem[131072];
    const int tid  = threadIdx.x;
    const int wid  = tid >> 6;          // 0..7
    const int lane = tid & 63;
    const int wm = wid >> 2;            // 0..1  (M half)
    const int wn = wid & 3;             // 0..3  (N quarter)
    const int fr = lane & 15;
    const int fq = lane >> 4;
    const int fr7 = fr & 7;
    const int srow8  = lane >> 3;                        // staging row-in-chunk
    const int cperm8 = ((lane & 7) ^ srow8) * 8;         // staging col perm (elements)

    // XCD-chunked bijective swizzle (nb divisible by 8 for both GEMMs)
    const int nbx = gridDim.x;
    const int nb  = nbx * gridDim.y;
    const int L   = blockIdx.y * nbx + blockIdx.x;
    const int q8  = nb >> 3;
    const int newid = (L & 7) * q8 + (L >> 3);
    const int tm = (newid / nbx) * 256;
    const int tn = (newid % nbx) * 256;

#define STAGE(ptr, ld, tile0, kt2, h, matbase)                                              \
    {                                                                                        \
        _Pragma("unroll")                                                                    \
        for (int j = 0; j < 2; ++j) {                                                        \
            const int c = wid * 2 + j;                                                       \
            const unsigned short* src = (ptr) +                                              \
                (size_t)((tile0) + (h) * 128 + c * 8 + srow8) * (ld) + (kt2) * 64 + cperm8;  \
            char* dst = (char*)smem + ((((kt2) & 1) << 16) | (matbase) | ((h) << 14) | (c << 10)); \
            gload_lds16(src, dst);                                                           \
        }                                                                                    \
    }
#define STAGE_A(kt2, h) STAGE(A, lda, tm, kt2, h, 0)
#define STAGE_B(kt2, h) STAGE(Bt, ldb, tn, kt2, h, 32768)

    const int sx0 = ((0 + fq) ^ fr7) << 4;              // ks=0 16B slot (swizzled)
    const int sx1 = ((4 + fq) ^ fr7) << 4;              // ks=1
    const int aoff = (wm << 14) + (fr << 7);
    const int boff = 32768 + ((wn >> 1) << 14) + ((((wn & 1) * 64) + fr) << 7);

    bf16x8 a[4][2], b0[2][2], b1[2][2];
    f32x4 acc[8][4] = {};

#define READ_A(kb, mh)                                                                       \
    { _Pragma("unroll")                                                                      \
      for (int i = 0; i < 4; ++i) {                                                          \
        a[i][0] = *(const bf16x8*)(smem + (kb) + aoff + (((mh) * 64 + i * 16) << 7) + sx0);  \
        a[i][1] = *(const bf16x8*)(smem + (kb) + aoff + (((mh) * 64 + i * 16) << 7) + sx1);  \
      } }
#define READ_B(kb, nh, breg)                                                                 \
    { _Pragma("unroll")                                                                      \
      for (int n2 = 0; n2 < 2; ++n2) {                                                       \
        breg[n2][0] = *(const bf16x8*)(smem + (kb) + boff + ((((nh) * 2 + n2) * 16) << 7) + sx0); \
        breg[n2][1] = *(const bf16x8*)(smem + (kb) + boff + ((((nh) * 2 + n2) * 16) << 7) + sx1); \
      } }
#define MFMA_Q(mh, nh, breg)                                                                 \
    { _Pragma("unroll")                                                                      \
      for (int i = 0; i < 4; ++i)                                                            \
        _Pragma("unroll")                                                                    \
        for (int n2 = 0; n2 < 2; ++n2) {                                                     \
          acc[(mh) * 4 + i][(nh) * 2 + n2] = __builtin_amdgcn_mfma_f32_16x16x32_bf16(        \
              a[i][0], breg[n2][0], acc[(mh) * 4 + i][(nh) * 2 + n2], 0, 0, 0);              \
          acc[(mh) * 4 + i][(nh) * 2 + n2] = __builtin_amdgcn_mfma_f32_16x16x32_bf16(        \
              a[i][1], breg[n2][1], acc[(mh) * 4 + i][(nh) * 2 + n2], 0, 0, 0);              \
        } }
#define SYNC_PRE()                                             \
    __builtin_amdgcn_s_barrier();                              \
    asm volatile("s_waitcnt lgkmcnt(0)" ::: "memory");         \
    __builtin_amdgcn_sched_barrier(0);                         \
    __builtin_amdgcn_s_setprio(1);
#define SYNC_POST()                                            \
    __builtin_amdgcn_s_setprio(0);                             \
    __builtin_amdgcn_s_barrier();

    // ---- prologue: kt0 fully + kt1's B halves; drain the kt0 stages ----
    STAGE_A(0, 0); STAGE_A(0, 1); STAGE_B(0, 0); STAGE_B(0, 1);
    STAGE_B(1, 0); STAGE_B(1, 1);
    asm volatile("s_waitcnt vmcnt(4)" ::: "memory");
    __builtin_amdgcn_s_barrier();

    for (int kt = 0; kt < NKT; ++kt) {
        const int kb = (kt & 1) << 16;
        // ---- P0 ----
        READ_A(kb, 0);
        READ_B(kb, 0, b0);
        if (kt < NKT - 1) STAGE_A(kt + 1, 0);
        asm volatile("s_waitcnt lgkmcnt(8)" ::: "memory");
        SYNC_PRE(); MFMA_Q(0, 0, b0); SYNC_POST();
        // ---- P1 ----
        READ_B(kb, 1, b1);
        if (kt < NKT - 1) STAGE_A(kt + 1, 1);
        SYNC_PRE(); MFMA_Q(0, 1, b1); SYNC_POST();
        // ---- P2 ----
        READ_A(kb, 1);
        if (kt < NKT - 2) STAGE_B(kt + 2, 0);
        SYNC_PRE(); MFMA_Q(1, 1, b1); SYNC_POST();
        // ---- P3 (no ds_read; uses regs a[mh1], b0) ----
        if (kt < NKT - 2) STAGE_B(kt + 2, 1);
        __builtin_amdgcn_s_barrier();
        __builtin_amdgcn_s_setprio(1); MFMA_Q(1, 0, b0); __builtin_amdgcn_s_setprio(0);
        if (kt < NKT - 2) { asm volatile("s_waitcnt vmcnt(4)" ::: "memory"); }
        else              { asm volatile("s_waitcnt vmcnt(0)" ::: "memory"); }
        __builtin_amdgcn_s_barrier();
    }

    // ---- epilogue ----
    if (FUSED) {
        const int kind = tn >> 10;   // 0=q, 1=k, 2=v
        if (kind == 0) {
            // q-softmax stats over the wave's 64 in-tile logits (one full head per wave)
            const int h = (tn >> 6) + wn;
#pragma unroll
            for (int mq = 0; mq < 8; ++mq) {
#pragma unroll
                for (int j = 0; j < 4; ++j) {
                    float mx = acc[mq][0][j];
#pragma unroll
                    for (int nf = 1; nf < 4; ++nf) mx = fmaxf(mx, acc[mq][nf][j]);
                    mx = fmaxf(mx, __shfl_xor(mx, 1));
                    mx = fmaxf(mx, __shfl_xor(mx, 2));
                    mx = fmaxf(mx, __shfl_xor(mx, 4));
                    mx = fmaxf(mx, __shfl_xor(mx, 8));
                    float sm = 0.f;
#pragma unroll
                    for (int nf = 0; nf < 4; ++nf) sm += __expf(acc[mq][nf][j] - mx);
                    sm += __shfl_xor(sm, 1);
                    sm += __shfl_xor(sm, 2);
                    sm += __shfl_xor(sm, 4);
                    sm += __shfl_xor(sm, 8);
                    const int r = tm + wm * 128 + mq * 16 + fq * 4 + j;
                    const float e64 = __expf(q64p[(size_t)r * 16 + h] - mx);
                    const float w = 2.0f * (1.0f - e64 / (sm + e64));
                    if (fr == 0) wfac[(size_t)r * 16 + h] = w;
                }
            }
        } else if (kind == 1) {
            // k-softmax in-register, store ksm bf16
            const int colbase = tn - 1024 + wn * 64;
#pragma unroll
            for (int mq = 0; mq < 8; ++mq) {
#pragma unroll
                for (int j = 0; j < 4; ++j) {
                    float mx = acc[mq][0][j];
#pragma unroll
                    for (int nf = 1; nf < 4; ++nf) mx = fmaxf(mx, acc[mq][nf][j]);
                    mx = fmaxf(mx, __shfl_xor(mx, 1));
                    mx = fmaxf(mx, __shfl_xor(mx, 2));
                    mx = fmaxf(mx, __shfl_xor(mx, 4));
                    mx = fmaxf(mx, __shfl_xor(mx, 8));
                    float e[4];
                    float sm = 0.f;
#pragma unroll
                    for (int nf = 0; nf < 4; ++nf) { e[nf] = __expf(acc[mq][nf][j] - mx); sm += e[nf]; }
                    sm += __shfl_xor(sm, 1);
                    sm += __shfl_xor(sm, 2);
                    sm += __shfl_xor(sm, 4);
                    sm += __shfl_xor(sm, 8);
                    const float inv = 1.0f / sm;
                    const int r = tm + wm * 128 + mq * 16 + fq * 4 + j;
#pragma unroll
                    for (int nf = 0; nf < 4; ++nf)
                        ((unsigned short*)Cout)[(size_t)r * ldc + colbase + nf * 16 + fr] = f2bf(e[nf] * inv);
                }
            }
        } else {
            // v: plain bf16 store
            const int colbase = tn - 1024 + wn * 64;
#pragma unroll
            for (int mq = 0; mq < 8; ++mq) {
                const int row0 = tm + wm * 128 + mq * 16 + fq * 4;
#pragma unroll
                for (int nf = 0; nf < 4; ++nf) {
                    const int col = colbase + nf * 16 + fr;
                    f32x4 v = acc[mq][nf];
#pragma unroll
                    for (int j = 0; j < 4; ++j)
                        ((unsigned short*)Cout)[(size_t)(row0 + j) * ldc + col] = f2bf(v[j]);
                }
            }
        }
    } else {
        // GEMM2: f32 + bias
#pragma unroll
        for (int mq = 0; mq < 8; ++mq) {
            const int row0 = tm + wm * 128 + mq * 16 + fq * 4;
#pragma unroll
            for (int nf = 0; nf < 4; ++nf) {
                const int col = tn + wn * 64 + nf * 16 + fr;
                f32x4 v = acc[mq][nf];
                const float bb = bias[col];
#pragma unroll
                for (int j = 0; j < 4; ++j)
                    ((float*)Cout)[(size_t)(row0 + j) * ldc + col] = v[j] + bb;
            }
        }
    }
#undef STAGE
#undef STAGE_A
#undef STAGE_B
#undef READ_A
#undef READ_B
#undef MFMA_Q
#undef SYNC_PRE
#undef SYNC_POST
}

// ---------------- gate: v *= wfac(t,h) * ksm(t,c) * mask(t), elementwise ----------------
// one wave per token; lane owns 16 consecutive cols (within one head since 16 | 64)
__global__ __launch_bounds__(256) void k_gate(unsigned short* __restrict__ C1,
                                              const float* __restrict__ wfac,
                                              const float* __restrict__ mask) {
    const int t    = blockIdx.x * 4 + (threadIdx.x >> 6);
    const int lane = threadIdx.x & 63;
    const int h    = lane >> 2;
    const float f  = wfac[(size_t)t * 16 + h] * mask[t];
    unsigned short* krow = C1 + (size_t)t * LDC1 + lane * 16;
    unsigned short* vrow = krow + 1024;
    const u16x8 k0 = *(const u16x8*)(krow);
    const u16x8 k1 = *(const u16x8*)(krow + 8);
    const u16x8 v0 = *(const u16x8*)(vrow);
    const u16x8 v1 = *(const u16x8*)(vrow + 8);
    u16x8 o0, o1;
#pragma unroll
    for (int j = 0; j < 8; ++j) {
        o0[j] = f2bf(f * bf2f(k0[j]) * bf2f(v0[j]));
        o1[j] = f2bf(f * bf2f(k1[j]) * bf2f(v1[j]));
    }
    *(u16x8*)(vrow)     = o0;
    *(u16x8*)(vrow + 8) = o1;
}

extern "C" void kernel_launch(void* const* d_in, const int* in_sizes, int n_in,
                              void* d_out, int out_size, void* d_ws, size_t ws_size,
                              hipStream_t stream) {
    (void)in_sizes; (void)n_in; (void)out_size; (void)ws_size;
    const float* x  = (const float*)d_in[0];
    const float* am = (const float*)d_in[1];
    const float* Wq = (const float*)d_in[2];
    const float* Wk = (const float*)d_in[3];
    const float* Wv = (const float*)d_in[4];
    const float* Wo = (const float*)d_in[5];
    const float* bo = (const float*)d_in[6];
    // time_angle / head_time_delta collapse to the constant 2 (see round-0 analysis)

    char* ws = (char*)d_ws;
    unsigned short* xb    = (unsigned short*)(ws);                 // 16384x1024 bf16   33,554,432 B
    unsigned short* Wall  = (unsigned short*)(ws + 33554432);      // 3072x1024 bf16     6,291,456 B
    unsigned short* Wq64b = (unsigned short*)(ws + 39845888);      // 16x1024 bf16          32,768 B
    unsigned short* Wob   = (unsigned short*)(ws + 39878656);      // 1024x1024 bf16     2,097,152 B
    float*          q64   = (float*)(ws + 41975808);               // 16384x16 f32       1,048,576 B
    float*          wfac  = (float*)(ws + 43024384);               // 16384x16 f32       1,048,576 B
    unsigned short* C1    = (unsigned short*)(ws + 44072960);      // 16384x2048 bf16   67,108,864 B

    // fused casts (x->bf16, Wall build, Wq64, Wo->bf16)
    k_cast_all<<<dim3((CASTN4 + 255) / 256), 256, 0, stream>>>(
        x, Wq, Wk, Wv, Wo, xb, Wall, Wq64b, Wob);

    // slot-64 q logits (needed by GEMM1's q-tile epilogue)
    k_q64<<<dim3(TOKENS / 4), 256, 0, stream>>>(xb, Wq64b, q64);

    // GEMM1 (fused epilogue): q->wfac, k->ksm, v->raw into C1[16384,2048]
    k_gemm256<1><<<dim3(NW / 256, TOKENS / 256), 512, 0, stream>>>(
        xb, DIM, Wall, DIM, C1, LDC1, nullptr, q64, wfac);

    // elementwise gate: v-section *= wfac * ksm * mask
    k_gate<<<dim3(TOKENS / 4), 256, 0, stream>>>(C1, wfac, am);

    // GEMM2: out[16384,1024] = g @ Wo^T + bo  (A = C1 v-section, lda=2048, f32 out)
    k_gemm256<0><<<dim3(DIM / 256, TOKENS / 256), 512, 0, stream>>>(
        C1 + 1024, LDC1, Wob, DIM, d_out, DIM, bo, nullptr, nullptr);
}

// Round 7
// 222.524 us; speedup vs baseline: 1.1657x; 1.0020x over previous
//
#include <hip/hip_runtime.h>
#include <cstdint>

#define TOKENS 16384   // b*l = 4*4096
#define DIM 1024
#define NW 3072        // GEMM1 N: q-slots0-63 (1024) | k (1024) | v (1024) = 12 x 256
#define LDC1P 2112     // C1 row stride in cols: [ksm 1024 | v 1024 | pad 64] = 4224B rows
                       // (non-power-of-2: spreads L2 sets; 4096B rows caused set-conflict refetch, r6)
#define NKT 16         // K = 1024 = 16 K-tiles of 64

typedef __bf16 bf16_t;
typedef bf16_t bf16x8 __attribute__((ext_vector_type(8)));
typedef unsigned short u16x8 __attribute__((ext_vector_type(8)));
typedef float f32x4 __attribute__((ext_vector_type(4)));

static __device__ __forceinline__ float bf2f(unsigned short u) {
    union { unsigned int i; float f; } v; v.i = ((unsigned int)u) << 16; return v.f;
}
static __device__ __forceinline__ unsigned short f2bf(float f) {
    unsigned int u = __float_as_uint(f);
    unsigned int r = u + 0x7FFFu + ((u >> 16) & 1u);   // RNE
    return (unsigned short)(r >> 16);
}

// async global->LDS, 16B/lane; LDS dest is wave-uniform base + lane*16B (linear).
static __device__ __forceinline__ void gload_lds16(const void* g, void* l) {
    __builtin_amdgcn_global_load_lds(
        (__attribute__((address_space(1))) void*)(uintptr_t)g,
        (__attribute__((address_space(3))) void*)(unsigned int)(uintptr_t)l,
        16, 0, 0);
}

// ---------------- merged cast kernel: x->xb | build Wall | Wq64 | Wo->Wob ----------------
// Wall[3072][1024]: rows [0,1024)=Wq(head h slot s -> h*65+s, s<64), [1024,2048)=Wk, [2048,3072)=Wv
// Wq64[16][1024]: Wq rows h*65+64 (per-head slot-64 projection)
#define XN4    (TOKENS * DIM / 4)           // 4,194,304
#define WALLN4 (NW * DIM / 4)               //   786,432
#define WQ64N4 (16 * DIM / 4)               //     4,096
#define WON4   (DIM * DIM / 4)              //   262,144
#define CASTN4 (XN4 + WALLN4 + WQ64N4 + WON4)
__global__ __launch_bounds__(256) void k_cast_all(const float* __restrict__ x,
                                                  const float* __restrict__ Wq,
                                                  const float* __restrict__ Wk,
                                                  const float* __restrict__ Wv,
                                                  const float* __restrict__ Wo,
                                                  unsigned short* __restrict__ xb,
                                                  unsigned short* __restrict__ Wall,
                                                  unsigned short* __restrict__ Wq64b,
                                                  unsigned short* __restrict__ Wob) {
    int i = blockIdx.x * 256 + threadIdx.x;
    if (i >= CASTN4) return;
    float4 v;
    unsigned short* dst;
    if (i < XN4) {
        v = ((const float4*)x)[i];
        dst = xb + (size_t)i * 4;
    } else if (i < XN4 + WALLN4) {
        int j = i - XN4;
        int c4 = j & 255;          // DIM/4 = 256
        int r  = j >> 8;
        if (r < 1024)            v = ((const float4*)Wq)[((r >> 6) * 65 + (r & 63)) * 256 + c4];
        else if (r < 2048)       v = ((const float4*)Wk)[(r - 1024) * 256 + c4];
        else                     v = ((const float4*)Wv)[(r - 2048) * 256 + c4];
        dst = Wall + (size_t)j * 4;
    } else if (i < XN4 + WALLN4 + WQ64N4) {
        int j = i - XN4 - WALLN4;
        int c4 = j & 255;
        int h  = j >> 8;
        v = ((const float4*)Wq)[(h * 65 + 64) * 256 + c4];
        dst = Wq64b + (size_t)j * 4;
    } else {
        int j = i - XN4 - WALLN4 - WQ64N4;
        v = ((const float4*)Wo)[j];
        dst = Wob + (size_t)j * 4;
    }
    ushort4 o;
    o.x = f2bf(v.x); o.y = f2bf(v.y); o.z = f2bf(v.z); o.w = f2bf(v.w);
    *(ushort4*)dst = o;
}

// ---------------- q64: per-token per-head slot-64 logit = dot(x_row, Wq64[h]) ----------------
__global__ __launch_bounds__(256) void k_q64(const unsigned short* __restrict__ xb,
                                             const unsigned short* __restrict__ Wq64,
                                             float* __restrict__ q64) {
    const int t    = blockIdx.x * 4 + (threadIdx.x >> 6);
    const int lane = threadIdx.x & 63;
    const unsigned short* xrow = xb + (size_t)t * DIM + lane * 16;
    const u16x8 xv0 = *(const u16x8*)(xrow);
    const u16x8 xv1 = *(const u16x8*)(xrow + 8);
    float xf[16];
#pragma unroll
    for (int j = 0; j < 8; ++j) { xf[j] = bf2f(xv0[j]); xf[8 + j] = bf2f(xv1[j]); }
#pragma unroll
    for (int h = 0; h < 16; ++h) {
        const unsigned short* wrow = Wq64 + (size_t)h * DIM + lane * 16;
        const u16x8 wv0 = *(const u16x8*)(wrow);
        const u16x8 wv1 = *(const u16x8*)(wrow + 8);
        float d = 0.f;
#pragma unroll
        for (int j = 0; j < 8; ++j)
            d += xf[j] * bf2f(wv0[j]) + xf[8 + j] * bf2f(wv1[j]);
        for (int o = 32; o; o >>= 1) d += __shfl_xor(d, o);
        if (lane == 0) q64[(size_t)t * 16 + h] = d;
    }
}

// ============ 256x256x(BK=64) 8-phase bf16 GEMM (verified K-loop, rounds 3-6) ============
// FUSED=1 (GEMM1): epilogue branches on tile kind (tn>>10):
//   q-tiles -> softmax stats + q64 -> wfac[t,h];  k-tiles -> ksm bf16;  v-tiles -> raw bf16
// FUSED=0 (GEMM2): f32 store + bias.
template<int FUSED>
__global__ __launch_bounds__(512, 2) void k_gemm256(const unsigned short* __restrict__ A, int lda,
                                                    const unsigned short* __restrict__ Bt, int ldb,
                                                    void* __restrict__ Cout, int ldc,
                                                    const float* __restrict__ bias,
                                                    const float* __restrict__ q64p,
                                                    float* __restrict__ wfac) {
    __shared__ char smem[131072];
    const int tid  = threadIdx.x;
    const int wid  = tid >> 6;          // 0..7
    const int lane = tid & 63;
    const int wm = wid >> 2;            // 0..1  (M half)
    const int wn = wid & 3;             // 0..3  (N quarter)
    const int fr = lane & 15;
    const int fq = lane >> 4;
    const int fr7 = fr & 7;
    const int srow8  = lane >> 3;                        // staging row-in-chunk
    const int cperm8 = ((lane & 7) ^ srow8) * 8;         // staging col perm (elements)

    // XCD-chunked bijective swizzle (nb divisible by 8 for both GEMMs)
    const int nbx = gridDim.x;
    const int nb  = nbx * gridDim.y;
    const int L   = blockIdx.y * nbx + blockIdx.x;
    const int q8  = nb >> 3;
    const int newid = (L & 7) * q8 + (L >> 3);
    const int tm = (newid / nbx) * 256;
    const int tn = (newid % nbx) * 256;

#define STAGE(ptr, ld, tile0, kt2, h, matbase)                                              \
    {                                                                                        \
        _Pragma("unroll")                                                                    \
        for (int j = 0; j < 2; ++j) {                                                        \
            const int c = wid * 2 + j;                                                       \
            const unsigned short* src = (ptr) +                                              \
                (size_t)((tile0) + (h) * 128 + c * 8 + srow8) * (ld) + (kt2) * 64 + cperm8;  \
            char* dst = (char*)smem + ((((kt2) & 1) << 16) | (matbase) | ((h) << 14) | (c << 10)); \
            gload_lds16(src, dst);                                                           \
        }                                                                                    \
    }
#define STAGE_A(kt2, h) STAGE(A, lda, tm, kt2, h, 0)
#define STAGE_B(kt2, h) STAGE(Bt, ldb, tn, kt2, h, 32768)

    const int sx0 = ((0 + fq) ^ fr7) << 4;              // ks=0 16B slot (swizzled)
    const int sx1 = ((4 + fq) ^ fr7) << 4;              // ks=1
    const int aoff = (wm << 14) + (fr << 7);
    const int boff = 32768 + ((wn >> 1) << 14) + ((((wn & 1) * 64) + fr) << 7);

    bf16x8 a[4][2], b0[2][2], b1[2][2];
    f32x4 acc[8][4] = {};

#define READ_A(kb, mh)                                                                       \
    { _Pragma("unroll")                                                                      \
      for (int i = 0; i < 4; ++i) {                                                          \
        a[i][0] = *(const bf16x8*)(smem + (kb) + aoff + (((mh) * 64 + i * 16) << 7) + sx0);  \
        a[i][1] = *(const bf16x8*)(smem + (kb) + aoff + (((mh) * 64 + i * 16) << 7) + sx1);  \
      } }
#define READ_B(kb, nh, breg)                                                                 \
    { _Pragma("unroll")                                                                      \
      for (int n2 = 0; n2 < 2; ++n2) {                                                       \
        breg[n2][0] = *(const bf16x8*)(smem + (kb) + boff + ((((nh) * 2 + n2) * 16) << 7) + sx0); \
        breg[n2][1] = *(const bf16x8*)(smem + (kb) + boff + ((((nh) * 2 + n2) * 16) << 7) + sx1); \
      } }
#define MFMA_Q(mh, nh, breg)                                                                 \
    { _Pragma("unroll")                                                                      \
      for (int i = 0; i < 4; ++i)                                                            \
        _Pragma("unroll")                                                                    \
        for (int n2 = 0; n2 < 2; ++n2) {                                                     \
          acc[(mh) * 4 + i][(nh) * 2 + n2] = __builtin_amdgcn_mfma_f32_16x16x32_bf16(        \
              a[i][0], breg[n2][0], acc[(mh) * 4 + i][(nh) * 2 + n2], 0, 0, 0);              \
          acc[(mh) * 4 + i][(nh) * 2 + n2] = __builtin_amdgcn_mfma_f32_16x16x32_bf16(        \
              a[i][1], breg[n2][1], acc[(mh) * 4 + i][(nh) * 2 + n2], 0, 0, 0);              \
        } }
#define SYNC_PRE()                                             \
    __builtin_amdgcn_s_barrier();                              \
    asm volatile("s_waitcnt lgkmcnt(0)" ::: "memory");         \
    __builtin_amdgcn_sched_barrier(0);                         \
    __builtin_amdgcn_s_setprio(1);
#define SYNC_POST()                                            \
    __builtin_amdgcn_s_setprio(0);                             \
    __builtin_amdgcn_s_barrier();

    // ---- prologue: kt0 fully + kt1's B halves; drain the kt0 stages ----
    STAGE_A(0, 0); STAGE_A(0, 1); STAGE_B(0, 0); STAGE_B(0, 1);
    STAGE_B(1, 0); STAGE_B(1, 1);
    asm volatile("s_waitcnt vmcnt(4)" ::: "memory");
    __builtin_amdgcn_s_barrier();

    for (int kt = 0; kt < NKT; ++kt) {
        const int kb = (kt & 1) << 16;
        // ---- P0 ----
        READ_A(kb, 0);
        READ_B(kb, 0, b0);
        if (kt < NKT - 1) STAGE_A(kt + 1, 0);
        asm volatile("s_waitcnt lgkmcnt(8)" ::: "memory");
        SYNC_PRE(); MFMA_Q(0, 0, b0); SYNC_POST();
        // ---- P1 ----
        READ_B(kb, 1, b1);
        if (kt < NKT - 1) STAGE_A(kt + 1, 1);
        SYNC_PRE(); MFMA_Q(0, 1, b1); SYNC_POST();
        // ---- P2 ----
        READ_A(kb, 1);
        if (kt < NKT - 2) STAGE_B(kt + 2, 0);
        SYNC_PRE(); MFMA_Q(1, 1, b1); SYNC_POST();
        // ---- P3 (no ds_read; uses regs a[mh1], b0) ----
        if (kt < NKT - 2) STAGE_B(kt + 2, 1);
        __builtin_amdgcn_s_barrier();
        __builtin_amdgcn_s_setprio(1); MFMA_Q(1, 0, b0); __builtin_amdgcn_s_setprio(0);
        if (kt < NKT - 2) { asm volatile("s_waitcnt vmcnt(4)" ::: "memory"); }
        else              { asm volatile("s_waitcnt vmcnt(0)" ::: "memory"); }
        __builtin_amdgcn_s_barrier();
    }

    // ---- epilogue ----
    if (FUSED) {
        const int kind = tn >> 10;   // 0=q, 1=k, 2=v
        if (kind == 0) {
            // q-softmax stats over the wave's 64 in-tile logits (one full head per wave)
            const int h = (tn >> 6) + wn;
#pragma unroll
            for (int mq = 0; mq < 8; ++mq) {
#pragma unroll
                for (int j = 0; j < 4; ++j) {
                    float mx = acc[mq][0][j];
#pragma unroll
                    for (int nf = 1; nf < 4; ++nf) mx = fmaxf(mx, acc[mq][nf][j]);
                    mx = fmaxf(mx, __shfl_xor(mx, 1));
                    mx = fmaxf(mx, __shfl_xor(mx, 2));
                    mx = fmaxf(mx, __shfl_xor(mx, 4));
                    mx = fmaxf(mx, __shfl_xor(mx, 8));
                    float sm = 0.f;
#pragma unroll
                    for (int nf = 0; nf < 4; ++nf) sm += __expf(acc[mq][nf][j] - mx);
                    sm += __shfl_xor(sm, 1);
                    sm += __shfl_xor(sm, 2);
                    sm += __shfl_xor(sm, 4);
                    sm += __shfl_xor(sm, 8);
                    const int r = tm + wm * 128 + mq * 16 + fq * 4 + j;
                    const float e64 = __expf(q64p[(size_t)r * 16 + h] - mx);
                    const float w = 2.0f * (1.0f - e64 / (sm + e64));
                    if (fr == 0) wfac[(size_t)r * 16 + h] = w;
                }
            }
        } else if (kind == 1) {
            // k-softmax in-register, store ksm bf16
            const int colbase = tn - 1024 + wn * 64;
#pragma unroll
            for (int mq = 0; mq < 8; ++mq) {
#pragma unroll
                for (int j = 0; j < 4; ++j) {
                    float mx = acc[mq][0][j];
#pragma unroll
                    for (int nf = 1; nf < 4; ++nf) mx = fmaxf(mx, acc[mq][nf][j]);
                    mx = fmaxf(mx, __shfl_xor(mx, 1));
                    mx = fmaxf(mx, __shfl_xor(mx, 2));
                    mx = fmaxf(mx, __shfl_xor(mx, 4));
                    mx = fmaxf(mx, __shfl_xor(mx, 8));
                    float e[4];
                    float sm = 0.f;
#pragma unroll
                    for (int nf = 0; nf < 4; ++nf) { e[nf] = __expf(acc[mq][nf][j] - mx); sm += e[nf]; }
                    sm += __shfl_xor(sm, 1);
                    sm += __shfl_xor(sm, 2);
                    sm += __shfl_xor(sm, 4);
                    sm += __shfl_xor(sm, 8);
                    const float inv = 1.0f / sm;
                    const int r = tm + wm * 128 + mq * 16 + fq * 4 + j;
#pragma unroll
                    for (int nf = 0; nf < 4; ++nf)
                        ((unsigned short*)Cout)[(size_t)r * ldc + colbase + nf * 16 + fr] = f2bf(e[nf] * inv);
                }
            }
        } else {
            // v: plain bf16 store
            const int colbase = tn - 1024 + wn * 64;
#pragma unroll
            for (int mq = 0; mq < 8; ++mq) {
                const int row0 = tm + wm * 128 + mq * 16 + fq * 4;
#pragma unroll
                for (int nf = 0; nf < 4; ++nf) {
                    const int col = colbase + nf * 16 + fr;
                    f32x4 v = acc[mq][nf];
#pragma unroll
                    for (int j = 0; j < 4; ++j)
                        ((unsigned short*)Cout)[(size_t)(row0 + j) * ldc + col] = f2bf(v[j]);
                }
            }
        }
    } else {
        // GEMM2: f32 + bias
#pragma unroll
        for (int mq = 0; mq < 8; ++mq) {
            const int row0 = tm + wm * 128 + mq * 16 + fq * 4;
#pragma unroll
            for (int nf = 0; nf < 4; ++nf) {
                const int col = tn + wn * 64 + nf * 16 + fr;
                f32x4 v = acc[mq][nf];
                const float bb = bias[col];
#pragma unroll
                for (int j = 0; j < 4; ++j)
                    ((float*)Cout)[(size_t)(row0 + j) * ldc + col] = v[j] + bb;
            }
        }
    }
#undef STAGE
#undef STAGE_A
#undef STAGE_B
#undef READ_A
#undef READ_B
#undef MFMA_Q
#undef SYNC_PRE
#undef SYNC_POST
}

// ---------------- gate: v *= wfac(t,h) * ksm(t,c) * mask(t), elementwise ----------------
__global__ __launch_bounds__(256) void k_gate(unsigned short* __restrict__ C1,
                                              const float* __restrict__ wfac,
                                              const float* __restrict__ mask) {
    const int t    = blockIdx.x * 4 + (threadIdx.x >> 6);
    const int lane = threadIdx.x & 63;
    const int h    = lane >> 2;
    const float f  = wfac[(size_t)t * 16 + h] * mask[t];
    unsigned short* krow = C1 + (size_t)t * LDC1P + lane * 16;
    unsigned short* vrow = krow + 1024;
    const u16x8 k0 = *(const u16x8*)(krow);
    const u16x8 k1 = *(const u16x8*)(krow + 8);
    const u16x8 v0 = *(const u16x8*)(vrow);
    const u16x8 v1 = *(const u16x8*)(vrow + 8);
    u16x8 o0, o1;
#pragma unroll
    for (int j = 0; j < 8; ++j) {
        o0[j] = f2bf(f * bf2f(k0[j]) * bf2f(v0[j]));
        o1[j] = f2bf(f * bf2f(k1[j]) * bf2f(v1[j]));
    }
    *(u16x8*)(vrow)     = o0;
    *(u16x8*)(vrow + 8) = o1;
}

extern "C" void kernel_launch(void* const* d_in, const int* in_sizes, int n_in,
                              void* d_out, int out_size, void* d_ws, size_t ws_size,
                              hipStream_t stream) {
    (void)in_sizes; (void)n_in; (void)out_size; (void)ws_size;
    const float* x  = (const float*)d_in[0];
    const float* am = (const float*)d_in[1];
    const float* Wq = (const float*)d_in[2];
    const float* Wk = (const float*)d_in[3];
    const float* Wv = (const float*)d_in[4];
    const float* Wo = (const float*)d_in[5];
    const float* bo = (const float*)d_in[6];
    // time_angle / head_time_delta collapse to the constant 2 (see round-0 analysis)

    char* ws = (char*)d_ws;
    unsigned short* xb    = (unsigned short*)(ws);                 // 16384x1024 bf16   33,554,432 B
    unsigned short* Wall  = (unsigned short*)(ws + 33554432);      // 3072x1024 bf16     6,291,456 B
    unsigned short* Wq64b = (unsigned short*)(ws + 39845888);      // 16x1024 bf16          32,768 B
    unsigned short* Wob   = (unsigned short*)(ws + 39878656);      // 1024x1024 bf16     2,097,152 B
    float*          q64   = (float*)(ws + 41975808);               // 16384x16 f32       1,048,576 B
    float*          wfac  = (float*)(ws + 43024384);               // 16384x16 f32       1,048,576 B
    unsigned short* C1    = (unsigned short*)(ws + 44072960);      // 16384x2112 bf16   69,206,016 B

    // fused casts (x->bf16, Wall build, Wq64, Wo->bf16)
    k_cast_all<<<dim3((CASTN4 + 255) / 256), 256, 0, stream>>>(
        x, Wq, Wk, Wv, Wo, xb, Wall, Wq64b, Wob);

    // slot-64 q logits (needed by GEMM1's q-tile epilogue)
    k_q64<<<dim3(TOKENS / 4), 256, 0, stream>>>(xb, Wq64b, q64);

    // GEMM1 (fused epilogue): q->wfac, k->ksm, v->raw into C1[16384,2112-stride]
    k_gemm256<1><<<dim3(NW / 256, TOKENS / 256), 512, 0, stream>>>(
        xb, DIM, Wall, DIM, C1, LDC1P, nullptr, q64, wfac);

    // elementwise gate: v-section *= wfac * ksm * mask
    k_gate<<<dim3(TOKENS / 4), 256, 0, stream>>>(C1, wfac, am);

    // GEMM2: out[16384,1024] = g @ Wo^T + bo  (A = C1 v-section, lda=2112, f32 out)
    k_gemm256<0><<<dim3(DIM / 256, TOKENS / 256), 512, 0, stream>>>(
        C1 + 1024, LDC1P, Wob, DIM, d_out, DIM, bo, nullptr, nullptr);
}